// Round 2
// baseline (439.917 us; speedup 1.0000x reference)
//
#include <hip/hip_runtime.h>
#include <hip/hip_bf16.h>

typedef __attribute__((ext_vector_type(8))) short short8;
typedef __attribute__((ext_vector_type(4))) float float4v;

#define NB 32
#define LL 128
#define DDIM 300
#define DP 320
#define KDIM 50
#define WP 328   // wtile pitch (bf16 elems)
#define TP 40    // T/e2t pitch

__device__ __forceinline__ unsigned short f2bf(float x) {
    unsigned int u = __float_as_uint(x);
    unsigned int r = (u + 0x7FFFu + ((u >> 16) & 1u)) >> 16;
    return (unsigned short)r;
}

__device__ __forceinline__ float4v mfma16(short8 a, short8 b, float4v c) {
    return __builtin_amdgcn_mfma_f32_16x16x32_bf16(a, b, c, 0, 0, 0);
}

// ---------- prep: e1/e2 -> bf16, D padded 300->320 with zeros (float4 loads) ----------
__global__ void prep_convert(const float* __restrict__ e1, const float* __restrict__ e2,
                             unsigned short* __restrict__ e1b, unsigned short* __restrict__ e2b) {
    int gid = blockIdx.x * 256 + threadIdx.x;     // 0..327679  (8192 rows * 40 granules)
    int row = gid / 40;
    int d0 = (gid % 40) * 8;
    const float* src;
    unsigned short* dst;
    if (row < 4096) { src = e1 + (size_t)row * DDIM; dst = e1b + (size_t)row * DP + d0; }
    else { int r = row - 4096; src = e2 + (size_t)r * DDIM; dst = e2b + (size_t)r * DP + d0; }
    float v[8];
    if (d0 + 8 <= DDIM) {               // full granule, 16B-aligned (rows are 1200B)
        float4 lo = *(const float4*)(src + d0);
        float4 hi = *(const float4*)(src + d0 + 4);
        v[0] = lo.x; v[1] = lo.y; v[2] = lo.z; v[3] = lo.w;
        v[4] = hi.x; v[5] = hi.y; v[6] = hi.z; v[7] = hi.w;
    } else if (d0 < DDIM) {             // d0 == 296: 4 valid + 4 pad
        float4 lo = *(const float4*)(src + d0);
        v[0] = lo.x; v[1] = lo.y; v[2] = lo.z; v[3] = lo.w;
        v[4] = v[5] = v[6] = v[7] = 0.f;
    } else {
        for (int j = 0; j < 8; ++j) v[j] = 0.f;
    }
    unsigned short tmp[8];
#pragma unroll
    for (int j = 0; j < 8; ++j) tmp[j] = f2bf(v[j]);
    *(short8*)dst = *(short8*)tmp;
}

// ---------- prep: Wb (k,d,e) fp32 -> Wbt (k,e,d) bf16, padded to 320x320 ----------
__global__ void prep_wbt(const float* __restrict__ Wb, unsigned short* __restrict__ wbt) {
    int k = blockIdx.x, dt = blockIdx.y, et = blockIdx.z;
    int tx = threadIdx.x & 31, ty = threadIdx.x >> 5;   // ty 0..7
    __shared__ float tile[32][33];
#pragma unroll
    for (int rr = 0; rr < 4; ++rr) {
        int d = dt * 32 + ty + rr * 8;
        int e = et * 32 + tx;
        tile[ty + rr * 8][tx] = (d < DDIM && e < DDIM) ? Wb[((size_t)k * DDIM + d) * DDIM + e] : 0.f;
    }
    __syncthreads();
#pragma unroll
    for (int rr = 0; rr < 4; ++rr) {
        int e = et * 32 + ty + rr * 8;
        int d = dt * 32 + tx;
        wbt[((size_t)k * DP + e) * DP + d] = f2bf(tile[tx][ty + rr * 8]);
    }
}

// ---------- prep: transpose Wd/Wg (600x50) -> (50x600) ----------
__global__ void prep_wt(const float* __restrict__ Wd, const float* __restrict__ Wg,
                        float* __restrict__ WdT, float* __restrict__ WgT) {
    int t = blockIdx.x * 256 + threadIdx.x;
    if (t >= KDIM * 2 * DDIM) return;          // 30000
    int kk = t / (2 * DDIM), d = t % (2 * DDIM);
    WdT[t] = Wd[(size_t)d * KDIM + kk];
    WgT[t] = Wg[(size_t)d * KDIM + kk];
}

// ---------- prep: gate/tanh projections, fast path (transposed W, float4, 4-way d-split) ----------
__global__ void prep_p_fast(const float* __restrict__ e1, const float* __restrict__ e2,
                            const float* __restrict__ WdT, const float* __restrict__ WgT,
                            float* __restrict__ p1d, float* __restrict__ p1g,
                            float* __restrict__ p2d, float* __restrict__ p2g) {
    int row = blockIdx.x;          // 0..8191
    int lane = threadIdx.x & 63, seg = threadIdx.x >> 6;   // 4 segs of 80 d (last 60)
    const float* src; int woff; float *dd, *dg; int r;
    if (row < 4096) { r = row; src = e1 + (size_t)r * DDIM; woff = 0; dd = p1d; dg = p1g; }
    else { r = row - 4096; src = e2 + (size_t)r * DDIM; woff = DDIM; dd = p2d; dg = p2g; }
    __shared__ float red[2][4][64];
    float ad = 0.f, ag = 0.f;
    if (lane < KDIM) {
        const float* wd = WdT + (size_t)lane * (2 * DDIM) + woff;
        const float* wg = WgT + (size_t)lane * (2 * DDIM) + woff;
        int d0 = seg * 80;
        int d1 = d0 + 80 > DDIM ? DDIM : d0 + 80;
        for (int d = d0; d < d1; d += 4) {
            float4 x = *(const float4*)(src + d);
            float4 a = *(const float4*)(wd + d);
            float4 b = *(const float4*)(wg + d);
            ad += x.x * a.x + x.y * a.y + x.z * a.z + x.w * a.w;
            ag += x.x * b.x + x.y * b.y + x.z * b.z + x.w * b.w;
        }
    }
    red[0][seg][lane] = ad;
    red[1][seg][lane] = ag;
    __syncthreads();
    if (threadIdx.x < 64 && lane < KDIM) {
        dd[(size_t)r * KDIM + lane] = red[0][0][lane] + red[0][1][lane] + red[0][2][lane] + red[0][3][lane];
        dg[(size_t)r * KDIM + lane] = red[1][0][lane] + red[1][1][lane] + red[1][2][lane] + red[1][3][lane];
    }
}

// ---------- prep: gate/tanh projections, fallback (no extra ws) ----------
__global__ void prep_p_slow(const float* __restrict__ e1, const float* __restrict__ e2,
                            const float* __restrict__ Wd, const float* __restrict__ Wg,
                            float* __restrict__ p1d, float* __restrict__ p1g,
                            float* __restrict__ p2d, float* __restrict__ p2g) {
    int row = blockIdx.x;
    int kk = threadIdx.x;
    if (kk >= KDIM) return;
    const float* src; int woff; float *dd, *dg; int r;
    if (row < 4096) { r = row; src = e1 + (size_t)r * DDIM; woff = 0; dd = p1d; dg = p1g; }
    else { r = row - 4096; src = e2 + (size_t)r * DDIM; woff = DDIM; dd = p2d; dg = p2g; }
    float ad = 0.f, ag = 0.f;
    for (int d = 0; d < DDIM; ++d) {
        float x = src[d];
        ad += x * Wd[(size_t)(woff + d) * KDIM + kk];
        ag += x * Wg[(size_t)(woff + d) * KDIM + kk];
    }
    dd[(size_t)r * KDIM + kk] = ad;
    dg[(size_t)r * KDIM + kk] = ag;
}

// ---------- main: per (b,k): S = (e1 Wb[k]) e2^T, gate, accumulate u[k]*mix ----------
// Register-prefetch pipeline: tile et+1's global loads are issued right after the
// post-staging barrier, so the vmcnt(0) drain at the end-of-compute barrier finds
// them complete (compute ~1.5k cyc >> L2 latency).
__global__ __launch_bounds__(256, 2) void grn_main(
    const unsigned short* __restrict__ e1b, const unsigned short* __restrict__ e2b,
    const unsigned short* __restrict__ wbt,
    const float* __restrict__ p1d, const float* __restrict__ p1g,
    const float* __restrict__ p2d, const float* __restrict__ p2g,
    const float* __restrict__ bg, const float* __restrict__ bb,
    const float* __restrict__ u, float* __restrict__ out) {
    const int b = blockIdx.x, k = blockIdx.y;
    const int tid = threadIdx.x;
    const int wid = tid >> 6, lane = tid & 63;
    const int q = lane >> 4, ln = lane & 15;
    const int rw0 = wid * 32;                      // wave owns S/T rows [rw0, rw0+32)

    __shared__ __align__(16) unsigned short wtile[32 * WP];   // Wbt tile [e'][d]
    __shared__ __align__(16) unsigned short Tt[128 * TP];     // T tile   [i][e']
    __shared__ __align__(16) unsigned short e2t[128 * TP];    // e2 tile  [j][e']
    __shared__ float pbuf[4][128];                            // p1d,p1g | p2d,p2g slices

    if (tid < 128) {
        int gi = (b * LL + tid) * KDIM + k;
        pbuf[0][tid] = p1d[gi];
        pbuf[1][tid] = p1g[gi];
        pbuf[2][tid] = p2d[gi];
        pbuf[3][tid] = p2g[gi];
    }
    const float u_k = u[k], bg_k = bg[k], b_k = bb[k];

    // per-thread staging offsets (constant across e-tiles)
    const unsigned short* wbt_k = wbt + (size_t)k * DP * DP;
    size_t wgo[5]; int wlo[5];
#pragma unroll
    for (int it = 0; it < 5; ++it) {
        int c = tid + it * 256, r = c / 40, col = (c % 40) * 8;
        wgo[it] = (size_t)r * DP + col;
        wlo[it] = r * WP + col;
    }
    size_t ego[2]; int elo[2];
#pragma unroll
    for (int it = 0; it < 2; ++it) {
        int c = tid + it * 256, j = c >> 2, col = (c & 3) * 8;
        ego[it] = (size_t)(b * LL + j) * DP + col;
        elo[it] = j * TP + col;
    }

    // e1 A-fragments, loaded once, reused across all e-tiles.
    short8 af[2][10];
#pragma unroll
    for (int mt = 0; mt < 2; ++mt) {
        int row = rw0 + mt * 16 + ln;
        const unsigned short* p = e1b + ((size_t)(b * LL + row)) * DP + q * 8;
#pragma unroll
        for (int kd = 0; kd < 10; ++kd)
            af[mt][kd] = *(const short8*)(p + kd * 32);
    }

    float4v S[2][8];
#pragma unroll
    for (int mt = 0; mt < 2; ++mt)
#pragma unroll
        for (int nt = 0; nt < 8; ++nt)
            S[mt][nt] = (float4v){0.f, 0.f, 0.f, 0.f};

    // prefetch tile 0
    short8 wpre[5], epre[2];
#pragma unroll
    for (int it = 0; it < 5; ++it) wpre[it] = *(const short8*)(wbt_k + wgo[it]);
#pragma unroll
    for (int it = 0; it < 2; ++it) epre[it] = *(const short8*)(e2b + ego[it]);

    for (int et = 0; et < 10; ++et) {
        // regs -> LDS (implicit vmcnt waits as each reg is consumed)
#pragma unroll
        for (int it = 0; it < 5; ++it) *(short8*)&wtile[wlo[it]] = wpre[it];
#pragma unroll
        for (int it = 0; it < 2; ++it) *(short8*)&e2t[elo[it]] = epre[it];
        __syncthreads();

        // issue next tile's global loads (latency hidden under compute below)
        if (et < 9) {
            const size_t ew = (size_t)(et + 1) * 32 * DP;
            const int ee = (et + 1) * 32;
#pragma unroll
            for (int it = 0; it < 5; ++it) wpre[it] = *(const short8*)(wbt_k + ew + wgo[it]);
#pragma unroll
            for (int it = 0; it < 2; ++it) epre[it] = *(const short8*)(e2b + ego[it] + ee);
        }

        // phase 1: T[i][e'] = sum_d e1[i][d] * Wbt[e'][d]
        float4v tacc[2][2];
#pragma unroll
        for (int mt = 0; mt < 2; ++mt)
#pragma unroll
            for (int nt = 0; nt < 2; ++nt)
                tacc[mt][nt] = (float4v){0.f, 0.f, 0.f, 0.f};
#pragma unroll
        for (int kd = 0; kd < 10; ++kd) {
            short8 bf0 = *(const short8*)&wtile[(ln) * WP + kd * 32 + q * 8];
            short8 bf1 = *(const short8*)&wtile[(16 + ln) * WP + kd * 32 + q * 8];
            tacc[0][0] = mfma16(af[0][kd], bf0, tacc[0][0]);
            tacc[0][1] = mfma16(af[0][kd], bf1, tacc[0][1]);
            tacc[1][0] = mfma16(af[1][kd], bf0, tacc[1][0]);
            tacc[1][1] = mfma16(af[1][kd], bf1, tacc[1][1]);
        }
        // write T to LDS (C layout: row = q*4+r, col = ln); rows are wave-private
#pragma unroll
        for (int mt = 0; mt < 2; ++mt)
#pragma unroll
            for (int nt = 0; nt < 2; ++nt)
#pragma unroll
                for (int r = 0; r < 4; ++r) {
                    int row = rw0 + mt * 16 + q * 4 + r;
                    Tt[row * TP + nt * 16 + ln] = f2bf(tacc[mt][nt][r]);
                }
        // phase 2: S[i][j] += sum_e' T[i][e'] * e2t[j][e']   (single K=32 step)
        short8 a0 = *(const short8*)&Tt[(rw0 + ln) * TP + q * 8];
        short8 a1 = *(const short8*)&Tt[(rw0 + 16 + ln) * TP + q * 8];
#pragma unroll
        for (int nt = 0; nt < 8; ++nt) {
            short8 bf = *(const short8*)&e2t[(nt * 16 + ln) * TP + q * 8];
            S[0][nt] = mfma16(a0, bf, S[0][nt]);
            S[1][nt] = mfma16(a1, bf, S[1][nt]);
        }
        __syncthreads();   // protect wtile/e2t before next iteration's writes
    }

    // epilogue: gate, mix, scale by u[k], atomic accumulate over k
    float pdi[2][4], pgi[2][4];
    size_t obase = (size_t)b * LL * LL;
#pragma unroll
    for (int mt = 0; mt < 2; ++mt)
#pragma unroll
        for (int r = 0; r < 4; ++r) {
            int i = rw0 + mt * 16 + q * 4 + r;
            pdi[mt][r] = pbuf[0][i];
            pgi[mt][r] = pbuf[1][i];
        }
#pragma unroll
    for (int nt = 0; nt < 8; ++nt) {
        int j = nt * 16 + ln;
        float pdj = pbuf[2][j];
        float pgj = pbuf[3][j] + bg_k;
#pragma unroll
        for (int mt = 0; mt < 2; ++mt)
#pragma unroll
            for (int r = 0; r < 4; ++r) {
                int i = rw0 + mt * 16 + q * 4 + r;
                float btp = S[mt][nt][r];
                float sd = pdi[mt][r] + pdj;
                float sg = pgi[mt][r] + pgj;
                float e2x = __expf(2.f * sd);
                float sln = 1.f - 2.f * __builtin_amdgcn_rcpf(e2x + 1.f);   // tanh(sd)
                float g = __builtin_amdgcn_rcpf(1.f + __expf(-sg));          // sigmoid(sg)
                float val = u_k * (g * btp + (1.f - g) * sln + b_k);
                unsafeAtomicAdd(out + obase + (size_t)i * LL + j, val);
            }
    }
}

extern "C" void kernel_launch(void* const* d_in, const int* in_sizes, int n_in,
                              void* d_out, int out_size, void* d_ws, size_t ws_size,
                              hipStream_t stream) {
    const float* e1 = (const float*)d_in[0];   // (32,128,300)
    const float* e2 = (const float*)d_in[1];   // (32,128,300)
    const float* Wb = (const float*)d_in[2];   // (50,300,300)
    const float* Wd = (const float*)d_in[3];   // (600,50)
    const float* Wg = (const float*)d_in[4];   // (600,50)
    const float* bg = (const float*)d_in[5];   // (50,)
    const float* bb = (const float*)d_in[6];   // (50,)
    const float* u  = (const float*)d_in[7];   // (50,1)
    float* out = (float*)d_out;                // (32,128,128,1)

    // workspace layout
    unsigned short* e1b = (unsigned short*)d_ws;                 // 1,310,720 elems
    unsigned short* e2b = e1b + 1310720;                         // 1,310,720 elems
    unsigned short* wbt = e2b + 1310720;                         // 5,120,000 elems
    float* pf  = (float*)((char*)d_ws + 15482880);
    float* p1d = pf;
    float* p1g = pf + 204800;
    float* p2d = pf + 409600;
    float* p2g = pf + 614400;                                    // end 18,759,680 B
    float* WdT = pf + 819200;                                    // 30,000 floats
    float* WgT = WdT + 30000;                                    // end 18,999,680 B

    hipMemsetAsync(d_out, 0, (size_t)out_size * sizeof(float), stream);

    prep_convert<<<1280, 256, 0, stream>>>(e1, e2, e1b, e2b);
    prep_wbt<<<dim3(KDIM, 10, 10), 256, 0, stream>>>(Wb, wbt);
    if (ws_size >= 18999680) {
        prep_wt<<<118, 256, 0, stream>>>(Wd, Wg, WdT, WgT);
        prep_p_fast<<<8192, 256, 0, stream>>>(e1, e2, WdT, WgT, p1d, p1g, p2d, p2g);
    } else {
        prep_p_slow<<<8192, 64, 0, stream>>>(e1, e2, Wd, Wg, p1d, p1g, p2d, p2g);
    }
    grn_main<<<dim3(NB, KDIM), 256, 0, stream>>>(e1b, e2b, wbt,
                                                 p1d, p1g, p2d, p2g,
                                                 bg, bb, u, out);
}

// Round 3
// 254.337 us; speedup vs baseline: 1.7297x; 1.7297x over previous
//
#include <hip/hip_runtime.h>
#include <hip/hip_bf16.h>

typedef __attribute__((ext_vector_type(8))) short short8;
typedef __attribute__((ext_vector_type(4))) float float4v;

#define NB 32
#define LL 128
#define DDIM 300
#define DP 320
#define KDIM 50
#define WP 328   // wtile pitch (bf16 elems)
#define TP 40    // T/e2t pitch

__device__ __forceinline__ unsigned short f2bf(float x) {
    unsigned int u = __float_as_uint(x);
    unsigned int r = (u + 0x7FFFu + ((u >> 16) & 1u)) >> 16;
    return (unsigned short)r;
}

__device__ __forceinline__ float4v mfma16(short8 a, short8 b, float4v c) {
    return __builtin_amdgcn_mfma_f32_16x16x32_bf16(a, b, c, 0, 0, 0);
}

// ---------- prep: e1/e2 -> bf16, D padded 300->320 with zeros (float4 loads) ----------
__global__ void prep_convert(const float* __restrict__ e1, const float* __restrict__ e2,
                             unsigned short* __restrict__ e1b, unsigned short* __restrict__ e2b) {
    int gid = blockIdx.x * 256 + threadIdx.x;     // 0..327679  (8192 rows * 40 granules)
    int row = gid / 40;
    int d0 = (gid % 40) * 8;
    const float* src;
    unsigned short* dst;
    if (row < 4096) { src = e1 + (size_t)row * DDIM; dst = e1b + (size_t)row * DP + d0; }
    else { int r = row - 4096; src = e2 + (size_t)r * DDIM; dst = e2b + (size_t)r * DP + d0; }
    float v[8];
    if (d0 + 8 <= DDIM) {               // full granule, 16B-aligned (rows are 1200B)
        float4 lo = *(const float4*)(src + d0);
        float4 hi = *(const float4*)(src + d0 + 4);
        v[0] = lo.x; v[1] = lo.y; v[2] = lo.z; v[3] = lo.w;
        v[4] = hi.x; v[5] = hi.y; v[6] = hi.z; v[7] = hi.w;
    } else if (d0 < DDIM) {             // d0 == 296: 4 valid + 4 pad
        float4 lo = *(const float4*)(src + d0);
        v[0] = lo.x; v[1] = lo.y; v[2] = lo.z; v[3] = lo.w;
        v[4] = v[5] = v[6] = v[7] = 0.f;
    } else {
        for (int j = 0; j < 8; ++j) v[j] = 0.f;
    }
    unsigned short tmp[8];
#pragma unroll
    for (int j = 0; j < 8; ++j) tmp[j] = f2bf(v[j]);
    *(short8*)dst = *(short8*)tmp;
}

// ---------- prep: Wb (k,d,e) fp32 -> Wbt (k,e,d) bf16, padded to 320x320 ----------
__global__ void prep_wbt(const float* __restrict__ Wb, unsigned short* __restrict__ wbt) {
    int k = blockIdx.x, dt = blockIdx.y, et = blockIdx.z;
    int tx = threadIdx.x & 31, ty = threadIdx.x >> 5;   // ty 0..7
    __shared__ float tile[32][33];
#pragma unroll
    for (int rr = 0; rr < 4; ++rr) {
        int d = dt * 32 + ty + rr * 8;
        int e = et * 32 + tx;
        tile[ty + rr * 8][tx] = (d < DDIM && e < DDIM) ? Wb[((size_t)k * DDIM + d) * DDIM + e] : 0.f;
    }
    __syncthreads();
#pragma unroll
    for (int rr = 0; rr < 4; ++rr) {
        int e = et * 32 + ty + rr * 8;
        int d = dt * 32 + tx;
        wbt[((size_t)k * DP + e) * DP + d] = f2bf(tile[tx][ty + rr * 8]);
    }
}

// ---------- prep: gate/tanh projections v3 ----------
// Coalesced over k (original W layout: lane k reads Wd[(d)*50+k], 200B/wave-load),
// e rows read as float4 broadcast (4 distinct 16B addrs per wave). 16 rows/block,
// 4 rows/thread, 8 fp32 accumulators. No LDS, no transpose.
__global__ void prep_p_v3(const float* __restrict__ e1, const float* __restrict__ e2,
                          const float* __restrict__ Wd, const float* __restrict__ Wg,
                          float* __restrict__ p1d, float* __restrict__ p1g,
                          float* __restrict__ p2d, float* __restrict__ p2g) {
    const int bid = blockIdx.x;                 // 0..511, 16 rows each
    const int kk = threadIdx.x & 63;
    const int grp = threadIdx.x >> 6;           // 0..3 -> 4 rows each
    const int kks = kk < KDIM ? kk : 0;         // clamp for safe OOB-free loads
    const float* src; int woff; float *dd, *dg; int r0;
    int rowbase = bid * 16;
    if (rowbase < 4096) { r0 = rowbase; src = e1; woff = 0; dd = p1d; dg = p1g; }
    else { r0 = rowbase - 4096; src = e2; woff = DDIM; dd = p2d; dg = p2g; }
    const float* e0 = src + (size_t)(r0 + grp * 4) * DDIM;
    const float* wdp = Wd + (size_t)woff * KDIM + kks;
    const float* wgp = Wg + (size_t)woff * KDIM + kks;

    float ad[4] = {0.f, 0.f, 0.f, 0.f}, ag[4] = {0.f, 0.f, 0.f, 0.f};
    for (int c = 0; c < DDIM / 4; ++c) {
        const int d0 = c * 4;
        float4 x[4];
#pragma unroll
        for (int rr = 0; rr < 4; ++rr)
            x[rr] = *(const float4*)(e0 + (size_t)rr * DDIM + d0);
        float wd0 = wdp[(size_t)(d0 + 0) * KDIM];
        float wd1 = wdp[(size_t)(d0 + 1) * KDIM];
        float wd2 = wdp[(size_t)(d0 + 2) * KDIM];
        float wd3 = wdp[(size_t)(d0 + 3) * KDIM];
        float wg0 = wgp[(size_t)(d0 + 0) * KDIM];
        float wg1 = wgp[(size_t)(d0 + 1) * KDIM];
        float wg2 = wgp[(size_t)(d0 + 2) * KDIM];
        float wg3 = wgp[(size_t)(d0 + 3) * KDIM];
#pragma unroll
        for (int rr = 0; rr < 4; ++rr) {
            ad[rr] += x[rr].x * wd0 + x[rr].y * wd1 + x[rr].z * wd2 + x[rr].w * wd3;
            ag[rr] += x[rr].x * wg0 + x[rr].y * wg1 + x[rr].z * wg2 + x[rr].w * wg3;
        }
    }
    if (kk < KDIM) {
#pragma unroll
        for (int rr = 0; rr < 4; ++rr) {
            size_t o = (size_t)(r0 + grp * 4 + rr) * KDIM + kk;
            dd[o] = ad[rr];
            dg[o] = ag[rr];
        }
    }
}

// ---------- main: per (b,k): S = (e1 Wb[k]) e2^T, gate, accumulate u[k]*mix ----------
// Register-prefetch pipeline: tile et+1's global loads are issued right after the
// post-staging barrier, so the vmcnt drain at the end-of-compute barrier finds
// them complete (compute ~1.5k cyc >> L2 latency).
__global__ __launch_bounds__(256, 2) void grn_main(
    const unsigned short* __restrict__ e1b, const unsigned short* __restrict__ e2b,
    const unsigned short* __restrict__ wbt,
    const float* __restrict__ p1d, const float* __restrict__ p1g,
    const float* __restrict__ p2d, const float* __restrict__ p2g,
    const float* __restrict__ bg, const float* __restrict__ bb,
    const float* __restrict__ u, float* __restrict__ out) {
    const int b = blockIdx.x, k = blockIdx.y;
    const int tid = threadIdx.x;
    const int wid = tid >> 6, lane = tid & 63;
    const int q = lane >> 4, ln = lane & 15;
    const int rw0 = wid * 32;                      // wave owns S/T rows [rw0, rw0+32)

    __shared__ __align__(16) unsigned short wtile[32 * WP];   // Wbt tile [e'][d]
    __shared__ __align__(16) unsigned short Tt[128 * TP];     // T tile   [i][e']
    __shared__ __align__(16) unsigned short e2t[128 * TP];    // e2 tile  [j][e']
    __shared__ float pbuf[4][128];                            // p1d,p1g | p2d,p2g slices

    if (tid < 128) {
        int gi = (b * LL + tid) * KDIM + k;
        pbuf[0][tid] = p1d[gi];
        pbuf[1][tid] = p1g[gi];
        pbuf[2][tid] = p2d[gi];
        pbuf[3][tid] = p2g[gi];
    }
    const float u_k = u[k], bg_k = bg[k], b_k = bb[k];

    // per-thread staging offsets (constant across e-tiles)
    const unsigned short* wbt_k = wbt + (size_t)k * DP * DP;
    size_t wgo[5]; int wlo[5];
#pragma unroll
    for (int it = 0; it < 5; ++it) {
        int c = tid + it * 256, r = c / 40, col = (c % 40) * 8;
        wgo[it] = (size_t)r * DP + col;
        wlo[it] = r * WP + col;
    }
    size_t ego[2]; int elo[2];
#pragma unroll
    for (int it = 0; it < 2; ++it) {
        int c = tid + it * 256, j = c >> 2, col = (c & 3) * 8;
        ego[it] = (size_t)(b * LL + j) * DP + col;
        elo[it] = j * TP + col;
    }

    // e1 A-fragments, loaded once, reused across all e-tiles.
    short8 af[2][10];
#pragma unroll
    for (int mt = 0; mt < 2; ++mt) {
        int row = rw0 + mt * 16 + ln;
        const unsigned short* p = e1b + ((size_t)(b * LL + row)) * DP + q * 8;
#pragma unroll
        for (int kd = 0; kd < 10; ++kd)
            af[mt][kd] = *(const short8*)(p + kd * 32);
    }

    float4v S[2][8];
#pragma unroll
    for (int mt = 0; mt < 2; ++mt)
#pragma unroll
        for (int nt = 0; nt < 8; ++nt)
            S[mt][nt] = (float4v){0.f, 0.f, 0.f, 0.f};

    // prefetch tile 0
    short8 wpre[5], epre[2];
#pragma unroll
    for (int it = 0; it < 5; ++it) wpre[it] = *(const short8*)(wbt_k + wgo[it]);
#pragma unroll
    for (int it = 0; it < 2; ++it) epre[it] = *(const short8*)(e2b + ego[it]);

    for (int et = 0; et < 10; ++et) {
        // regs -> LDS (implicit vmcnt waits as each reg is consumed)
#pragma unroll
        for (int it = 0; it < 5; ++it) *(short8*)&wtile[wlo[it]] = wpre[it];
#pragma unroll
        for (int it = 0; it < 2; ++it) *(short8*)&e2t[elo[it]] = epre[it];
        __syncthreads();

        // issue next tile's global loads (latency hidden under compute below)
        if (et < 9) {
            const size_t ew = (size_t)(et + 1) * 32 * DP;
            const int ee = (et + 1) * 32;
#pragma unroll
            for (int it = 0; it < 5; ++it) wpre[it] = *(const short8*)(wbt_k + ew + wgo[it]);
#pragma unroll
            for (int it = 0; it < 2; ++it) epre[it] = *(const short8*)(e2b + ego[it] + ee);
        }

        // phase 1: T[i][e'] = sum_d e1[i][d] * Wbt[e'][d]
        float4v tacc[2][2];
#pragma unroll
        for (int mt = 0; mt < 2; ++mt)
#pragma unroll
            for (int nt = 0; nt < 2; ++nt)
                tacc[mt][nt] = (float4v){0.f, 0.f, 0.f, 0.f};
#pragma unroll
        for (int kd = 0; kd < 10; ++kd) {
            short8 bf0 = *(const short8*)&wtile[(ln) * WP + kd * 32 + q * 8];
            short8 bf1 = *(const short8*)&wtile[(16 + ln) * WP + kd * 32 + q * 8];
            tacc[0][0] = mfma16(af[0][kd], bf0, tacc[0][0]);
            tacc[0][1] = mfma16(af[0][kd], bf1, tacc[0][1]);
            tacc[1][0] = mfma16(af[1][kd], bf0, tacc[1][0]);
            tacc[1][1] = mfma16(af[1][kd], bf1, tacc[1][1]);
        }
        // write T to LDS (C layout: row = q*4+r, col = ln); rows are wave-private
#pragma unroll
        for (int mt = 0; mt < 2; ++mt)
#pragma unroll
            for (int nt = 0; nt < 2; ++nt)
#pragma unroll
                for (int r = 0; r < 4; ++r) {
                    int row = rw0 + mt * 16 + q * 4 + r;
                    Tt[row * TP + nt * 16 + ln] = f2bf(tacc[mt][nt][r]);
                }
        // phase 2: S[i][j] += sum_e' T[i][e'] * e2t[j][e']   (single K=32 step)
        short8 a0 = *(const short8*)&Tt[(rw0 + ln) * TP + q * 8];
        short8 a1 = *(const short8*)&Tt[(rw0 + 16 + ln) * TP + q * 8];
#pragma unroll
        for (int nt = 0; nt < 8; ++nt) {
            short8 bf = *(const short8*)&e2t[(nt * 16 + ln) * TP + q * 8];
            S[0][nt] = mfma16(a0, bf, S[0][nt]);
            S[1][nt] = mfma16(a1, bf, S[1][nt]);
        }
        __syncthreads();   // protect wtile/e2t before next iteration's writes
    }

    // epilogue: gate, mix, scale by u[k], atomic accumulate over k
    float pdi[2][4], pgi[2][4];
    size_t obase = (size_t)b * LL * LL;
#pragma unroll
    for (int mt = 0; mt < 2; ++mt)
#pragma unroll
        for (int r = 0; r < 4; ++r) {
            int i = rw0 + mt * 16 + q * 4 + r;
            pdi[mt][r] = pbuf[0][i];
            pgi[mt][r] = pbuf[1][i];
        }
#pragma unroll
    for (int nt = 0; nt < 8; ++nt) {
        int j = nt * 16 + ln;
        float pdj = pbuf[2][j];
        float pgj = pbuf[3][j] + bg_k;
#pragma unroll
        for (int mt = 0; mt < 2; ++mt)
#pragma unroll
            for (int r = 0; r < 4; ++r) {
                int i = rw0 + mt * 16 + q * 4 + r;
                float btp = S[mt][nt][r];
                float sd = pdi[mt][r] + pdj;
                float sg = pgi[mt][r] + pgj;
                float e2x = __expf(2.f * sd);
                float sln = 1.f - 2.f * __builtin_amdgcn_rcpf(e2x + 1.f);   // tanh(sd)
                float g = __builtin_amdgcn_rcpf(1.f + __expf(-sg));          // sigmoid(sg)
                float val = u_k * (g * btp + (1.f - g) * sln + b_k);
                unsafeAtomicAdd(out + obase + (size_t)i * LL + j, val);
            }
    }
}

extern "C" void kernel_launch(void* const* d_in, const int* in_sizes, int n_in,
                              void* d_out, int out_size, void* d_ws, size_t ws_size,
                              hipStream_t stream) {
    const float* e1 = (const float*)d_in[0];   // (32,128,300)
    const float* e2 = (const float*)d_in[1];   // (32,128,300)
    const float* Wb = (const float*)d_in[2];   // (50,300,300)
    const float* Wd = (const float*)d_in[3];   // (600,50)
    const float* Wg = (const float*)d_in[4];   // (600,50)
    const float* bg = (const float*)d_in[5];   // (50,)
    const float* bb = (const float*)d_in[6];   // (50,)
    const float* u  = (const float*)d_in[7];   // (50,1)
    float* out = (float*)d_out;                // (32,128,128,1)

    // workspace layout
    unsigned short* e1b = (unsigned short*)d_ws;                 // 1,310,720 elems
    unsigned short* e2b = e1b + 1310720;                         // 1,310,720 elems
    unsigned short* wbt = e2b + 1310720;                         // 5,120,000 elems
    float* pf  = (float*)((char*)d_ws + 15482880);
    float* p1d = pf;
    float* p1g = pf + 204800;
    float* p2d = pf + 409600;
    float* p2g = pf + 614400;                                    // end 18,759,680 B

    hipMemsetAsync(d_out, 0, (size_t)out_size * sizeof(float), stream);

    prep_convert<<<1280, 256, 0, stream>>>(e1, e2, e1b, e2b);
    prep_wbt<<<dim3(KDIM, 10, 10), 256, 0, stream>>>(Wb, wbt);
    prep_p_v3<<<512, 256, 0, stream>>>(e1, e2, Wd, Wg, p1d, p1g, p2d, p2g);
    grn_main<<<dim3(NB, KDIM), 256, 0, stream>>>(e1b, e2b, wbt,
                                                 p1d, p1g, p2d, p2g,
                                                 bg, bb, u, out);
}